// Round 10
// baseline (70.454 us; speedup 1.0000x reference)
//
#include <hip/hip_runtime.h>
#include <hip/hip_fp16.h>

#define PP 7
#define SR 2
#define HH 128
#define WW 128
#define CC 256
#define PLANE (HH * WW)
#define CPW 8      // channels per wave
#define NCHUNK 8   // chunks per ROI (32 ch each); chunk id ~ XCD id
#define NSLOT 3    // LDS ring slots per wave (depth-2 pipeline)

typedef const __attribute__((address_space(1))) void g_void;
typedef __attribute__((address_space(3))) void l_void;

// Async global->LDS, 16B/lane: LDS dest = wave-uniform base + lane*16,
// global src per-lane. Fire-and-forget vs vmcnt -> MLP independent of regalloc.
__device__ __forceinline__ void gload_lds16(const float* g, float* lds_base) {
  __builtin_amdgcn_global_load_lds((g_void*)g, (l_void*)lds_base, 16, 0, 0);
}

__global__ __launch_bounds__(256, 4) void roi_pool_kernel(
    const float* __restrict__ fm, const float* __restrict__ rois,
    float* __restrict__ out, int N) {
  const int bid = blockIdx.x;
  const int chunk = bid & 7;          // ~XCD id: each XCD streams a 32-ch slice
  const int roi = bid >> 3;
  const int t = threadIdx.x;
  const int wave = t >> 6;
  const int lane = t & 63;

  __shared__ float4 stage[4][NSLOT][4][64];   // 48 KB: 3-slot ring x 4ch / wave
  __shared__ float WX[WW], WY[HH];
  __shared__ int rowIdx[32];
  __shared__ float rowW[32];

  if (t < 128) { WX[t] = 0.f; WY[t] = 0.f; }
  __syncthreads();

  // ---- geometry (redundant per-thread) ----
  const float bf = rois[roi * 6 + 0];
  const float cx = rois[roi * 6 + 2];
  const float cy = rois[roi * 6 + 3];
  const float w_ = rois[roi * 6 + 4];
  const float h_ = rois[roi * 6 + 5];

  // f16 round-trip, contraction-free (match jnp float16 cast semantics)
  const float x1 = __half2float(__float2half(
      __fmul_rn(__fsub_rn(cx, __fmul_rn(0.5f, w_)), 128.0f)));
  const float y1 = __half2float(__float2half(
      __fmul_rn(__fsub_rn(cy, __fmul_rn(0.5f, h_)), 128.0f)));
  const float x2 = __half2float(__float2half(
      __fmul_rn(__fadd_rn(cx, __fmul_rn(0.5f, w_)), 128.0f)));
  const float y2 = __half2float(__float2half(
      __fmul_rn(__fadd_rn(cy, __fmul_rn(0.5f, h_)), 128.0f)));

  const float sx = fmaxf(__fsub_rn(x2, x1), 1.0f) / 7.0f;
  const float sy = fmaxf(__fsub_rn(y2, y1), 1.0f) / 7.0f;

  // ---- scatter per-axis sample weights (threads 0..27, all in wave 0) ----
  if (t < 2 * PP * SR) {
    const int isX = t >= PP * SR;
    const int i = t - isX * PP * SR;             // 0..13
    const float off = (float)(i >> 1) + ((float)(i & 1) + 0.5f) * 0.5f;
    const float pos = __fadd_rn(isX ? x1 : y1, __fmul_rn(off, isX ? sx : sy));
    if (pos > -1.0f && pos < 128.0f) {
      const float pc = fminf(fmaxf(pos, 0.0f), 127.0f);
      const int p0 = (int)floorf(pc);
      const int p1 = min(p0 + 1, 127);
      const float l = pc - (float)p0;
      float* Warr = isX ? WX : WY;
      atomicAdd(&Warr[p0], 1.0f - l);
      atomicAdd(&Warr[p1], l);
    }
  }
  __syncthreads();

  // ---- per-wave ballot compaction (identical results in every wave) ----
  const float wy0 = WY[lane], wy1 = WY[lane + 64];
  const unsigned long long by0 = __ballot(wy0 != 0.f);
  const unsigned long long by1 = __ballot(wy1 != 0.f);
  const unsigned long long below = (lane == 0) ? 0ull : (~0ull >> (64 - lane));
  const int n0 = __popcll(by0);
  if (wave == 0) {
    if (wy0 != 0.f) { const int p = __popcll(by0 & below); rowIdx[p] = lane; rowW[p] = wy0; }
    if (wy1 != 0.f) { const int p = n0 + __popcll(by1 & below); rowIdx[p] = lane + 64; rowW[p] = wy1; }
  }
  const int nrows = n0 + __popcll(by1);

  const float wxa = WX[lane], wxb = WX[lane + 64];
  const unsigned long long bx0 = __ballot(wxa != 0.f);
  const unsigned long long bx1 = __ballot(wxb != 0.f);
  const int xlo = bx0 ? __builtin_ctzll(bx0) : (bx1 ? 64 + __builtin_ctzll(bx1) : 0);
  const int xhi = bx1 ? 64 + (63 - __builtin_clzll(bx1))
                      : (bx0 ? (63 - __builtin_clzll(bx0)) : -1);
  __syncthreads();

  float acc[CPW];
  #pragma unroll
  for (int c = 0; c < CPW; ++c) acc[c] = 0.f;

  const int c0 = chunk * 32 + wave * CPW;

  if (nrows > 0 && xhi >= 0) {          // wave-uniform branch
    const int b = (int)bf;
    const int x4lo = xlo >> 2;
    const int x4cnt = (xhi >> 2) - x4lo + 1;                    // <= 15
    const int l2 = (x4cnt <= 1) ? 0 : (32 - __clz(x4cnt - 1));  // ceil log2
    const int nx4 = 1 << l2;
    const int rowstep = 64 >> l2;
    const int xi = lane & (nx4 - 1);
    const int ri = lane >> l2;
    const bool xv = xi < x4cnt;
    const int col4 = xv ? (x4lo + xi) : x4lo;                   // dup lanes share line
    float4 wx4 = make_float4(0.f, 0.f, 0.f, 0.f);
    if (xv) wx4 = *(const float4*)&WX[col4 << 2];
    const float* cb = fm + ((size_t)b * CC + c0) * PLANE + (col4 << 2);

    const int ngroups = (nrows + rowstep - 1) >> (6 - l2);
    const int NB = ngroups * 2;         // batches: (row-group) x (channel half)

    // batch k: row-group g=k>>1, channel-half h=k&1, ring slot k%3
    auto ISSUE = [&](int k) {
      const int g = k >> 1, h = k & 1, slot = k % NSLOT;
      const int idx = min(g * rowstep + ri, nrows - 1);
      const int row = rowIdx[idx];                 // clamped lanes: weight 0 later
      const float* p = cb + row * WW + (h * 4) * PLANE;
      float* sb = (float*)&stage[wave][slot][0][0];
      gload_lds16(p,             sb);
      gload_lds16(p + PLANE,     sb + 256);
      gload_lds16(p + 2 * PLANE, sb + 512);
      gload_lds16(p + 3 * PLANE, sb + 768);
    };
    auto CONSUME = [&](int k) {
      const int g = k >> 1, slot = k % NSLOT;
      const int si = g * rowstep + ri;
      const int idx = min(si, nrows - 1);
      const float wy = (si < nrows) ? rowW[idx] : 0.f;
      const float w0 = wx4.x * wy, w1 = wx4.y * wy;
      const float w2 = wx4.z * wy, w3 = wx4.w * wy;
      const float4 v0 = stage[wave][slot][0][lane];
      const float4 v1 = stage[wave][slot][1][lane];
      const float4 v2 = stage[wave][slot][2][lane];
      const float4 v3 = stage[wave][slot][3][lane];
      if (k & 1) {
        float a;
        a = acc[4]; a = fmaf(w0,v0.x,a); a = fmaf(w1,v0.y,a); a = fmaf(w2,v0.z,a); a = fmaf(w3,v0.w,a); acc[4] = a;
        a = acc[5]; a = fmaf(w0,v1.x,a); a = fmaf(w1,v1.y,a); a = fmaf(w2,v1.z,a); a = fmaf(w3,v1.w,a); acc[5] = a;
        a = acc[6]; a = fmaf(w0,v2.x,a); a = fmaf(w1,v2.y,a); a = fmaf(w2,v2.z,a); a = fmaf(w3,v2.w,a); acc[6] = a;
        a = acc[7]; a = fmaf(w0,v3.x,a); a = fmaf(w1,v3.y,a); a = fmaf(w2,v3.z,a); a = fmaf(w3,v3.w,a); acc[7] = a;
      } else {
        float a;
        a = acc[0]; a = fmaf(w0,v0.x,a); a = fmaf(w1,v0.y,a); a = fmaf(w2,v0.z,a); a = fmaf(w3,v0.w,a); acc[0] = a;
        a = acc[1]; a = fmaf(w0,v1.x,a); a = fmaf(w1,v1.y,a); a = fmaf(w2,v1.z,a); a = fmaf(w3,v1.w,a); acc[1] = a;
        a = acc[2]; a = fmaf(w0,v2.x,a); a = fmaf(w1,v2.y,a); a = fmaf(w2,v2.z,a); a = fmaf(w3,v2.w,a); acc[2] = a;
        a = acc[3]; a = fmaf(w0,v3.x,a); a = fmaf(w1,v3.y,a); a = fmaf(w2,v3.z,a); a = fmaf(w3,v3.w,a); acc[3] = a;
      }
    };

    // depth-2 counted-vmcnt pipeline (T3/T4): never drain to 0 in steady state
    ISSUE(0);
    if (NB > 1) ISSUE(1);
    for (int k = 0; k < NB; ++k) {
      if (k + 2 < NB) {
        ISSUE(k + 2);
        asm volatile("s_waitcnt vmcnt(8)" ::: "memory");   // batch k landed
      } else if (k + 1 < NB) {
        asm volatile("s_waitcnt vmcnt(4)" ::: "memory");
      } else {
        asm volatile("s_waitcnt vmcnt(0)" ::: "memory");
      }
      __builtin_amdgcn_sched_barrier(0);
      CONSUME(k);
      __builtin_amdgcn_sched_barrier(0);
    }
  }

  // ---- 64-lane reduce per channel, lane c writes channel c ----
  const size_t obase = (size_t)roi * CC + c0;
  #pragma unroll
  for (int c = 0; c < CPW; ++c) {
    float v = acc[c];
    #pragma unroll
    for (int m = 32; m >= 1; m >>= 1) v += __shfl_xor(v, m, 64);
    if (lane == c) out[obase + c] = v * (1.0f / 196.0f);
  }

  // ---- gt output ----
  if (chunk == 0 && t == 0) out[(size_t)N * CC + roi] = rois[roi * 6 + 1];
}

extern "C" void kernel_launch(void* const* d_in, const int* in_sizes, int n_in,
                              void* d_out, int out_size, void* d_ws, size_t ws_size,
                              hipStream_t stream) {
  const float* fm   = (const float*)d_in[0];
  const float* rois = (const float*)d_in[1];
  float* out = (float*)d_out;
  const int N = in_sizes[1] / 6;
  roi_pool_kernel<<<N * NCHUNK, 256, 0, stream>>>(fm, rois, out, N);
}

// Round 11
// 51.900 us; speedup vs baseline: 1.3575x; 1.3575x over previous
//
#include <hip/hip_runtime.h>
#include <hip/hip_fp16.h>

#define PP 7
#define SR 2
#define HH 128
#define WW 128
#define CC 256
#define PLANE (HH * WW)
#define CPW 8      // channels per wave
#define NCHUNK 8   // chunks per ROI (32 ch each); chunk id ~ XCD id
#define MSTRIDE 208  // floats per ROI in ws: I[0..3]=b,l2,ngroups,x4lo;
                     // W[4..67]=rowW[64]; I[68..131]=rowOff[64]; W[136..199]=wx4[16]

typedef const __attribute__((address_space(1))) void g_void;
typedef __attribute__((address_space(3))) void l_void;

__device__ __forceinline__ void gload_lds16(const float* g, float* lds_base) {
  __builtin_amdgcn_global_load_lds((g_void*)g, (l_void*)lds_base, 16, 0, 0);
}

// ---------- Kernel A: per-ROI metadata (one 64-thread block per ROI) ----------
__global__ __launch_bounds__(64) void roi_meta_kernel(
    const float* __restrict__ rois, float* __restrict__ ws,
    float* __restrict__ out, int N) {
  const int roi = blockIdx.x;
  const int lane = threadIdx.x;

  __shared__ float WX[WW], WY[HH];
  __shared__ float rowWs[64];
  __shared__ int rowOffs[64];

  WX[lane] = 0.f; WX[lane + 64] = 0.f;
  WY[lane] = 0.f; WY[lane + 64] = 0.f;
  rowWs[lane] = 0.f; rowOffs[lane] = 0;
  __syncthreads();

  const float bf = rois[roi * 6 + 0];
  const float cx = rois[roi * 6 + 2];
  const float cy = rois[roi * 6 + 3];
  const float w_ = rois[roi * 6 + 4];
  const float h_ = rois[roi * 6 + 5];

  // f16 round-trip, contraction-free (match jnp float16 cast semantics)
  const float x1 = __half2float(__float2half(
      __fmul_rn(__fsub_rn(cx, __fmul_rn(0.5f, w_)), 128.0f)));
  const float y1 = __half2float(__float2half(
      __fmul_rn(__fsub_rn(cy, __fmul_rn(0.5f, h_)), 128.0f)));
  const float x2 = __half2float(__float2half(
      __fmul_rn(__fadd_rn(cx, __fmul_rn(0.5f, w_)), 128.0f)));
  const float y2 = __half2float(__float2half(
      __fmul_rn(__fadd_rn(cy, __fmul_rn(0.5f, h_)), 128.0f)));

  const float sx = fmaxf(__fsub_rn(x2, x1), 1.0f) / 7.0f;
  const float sy = fmaxf(__fsub_rn(y2, y1), 1.0f) / 7.0f;

  if (lane < 2 * PP * SR) {
    const int isX = lane >= PP * SR;
    const int i = lane - isX * PP * SR;          // 0..13
    const float off = (float)(i >> 1) + ((float)(i & 1) + 0.5f) * 0.5f;
    const float pos = __fadd_rn(isX ? x1 : y1, __fmul_rn(off, isX ? sx : sy));
    if (pos > -1.0f && pos < 128.0f) {
      const float pc = fminf(fmaxf(pos, 0.0f), 127.0f);
      const int p0 = (int)floorf(pc);
      const int p1 = min(p0 + 1, 127);
      const float l = pc - (float)p0;
      float* Warr = isX ? WX : WY;
      atomicAdd(&Warr[p0], 1.0f - l);
      atomicAdd(&Warr[p1], l);
    }
  }
  __syncthreads();

  // ballot compaction of nonzero rows into LDS (barrier-ordered, race-free)
  const float wy0 = WY[lane], wy1 = WY[lane + 64];
  const unsigned long long by0 = __ballot(wy0 != 0.f);
  const unsigned long long by1 = __ballot(wy1 != 0.f);
  const unsigned long long below = (lane == 0) ? 0ull : (~0ull >> (64 - lane));
  const int n0 = __popcll(by0);
  if (wy0 != 0.f) { const int p = __popcll(by0 & below); rowWs[p] = wy0; rowOffs[p] = lane * WW; }
  if (wy1 != 0.f) { const int p = n0 + __popcll(by1 & below); rowWs[p] = wy1; rowOffs[p] = (lane + 64) * WW; }
  const int nrows = n0 + __popcll(by1);

  const float wxa = WX[lane], wxb = WX[lane + 64];
  const unsigned long long bx0 = __ballot(wxa != 0.f);
  const unsigned long long bx1 = __ballot(wxb != 0.f);
  const int xlo = bx0 ? __builtin_ctzll(bx0) : (bx1 ? 64 + __builtin_ctzll(bx1) : 0);
  const int xhi = bx1 ? 64 + (63 - __builtin_clzll(bx1))
                      : (bx0 ? (63 - __builtin_clzll(bx0)) : -1);
  __syncthreads();

  const bool ok = (nrows > 0) && (xhi >= 0);
  const int x4lo = ok ? (xlo >> 2) : 0;
  const int x4cnt = ok ? ((xhi >> 2) - x4lo + 1) : 0;             // <= 15
  const int l2 = (x4cnt <= 1) ? 0 : (32 - __clz(x4cnt - 1));      // ceil log2
  const int rowstep = 64 >> l2;
  const int ngroups = ok ? ((nrows + rowstep - 1) >> (6 - l2)) : 0;

  float* W = ws + (size_t)roi * MSTRIDE;
  int* I = (int*)W;
  W[4 + lane] = rowWs[lane];
  I[68 + lane] = rowOffs[lane];
  if (lane < 16) {
    float4 v = make_float4(0.f, 0.f, 0.f, 0.f);
    if (lane < x4cnt) {
      const int xb = (x4lo + lane) << 2;
      v = make_float4(WX[xb], WX[xb + 1], WX[xb + 2], WX[xb + 3]);
    }
    *(float4*)(W + 136 + (lane << 2)) = v;
  }
  if (lane == 0) {
    I[0] = (int)bf; I[1] = l2; I[2] = ngroups; I[3] = x4lo;
    out[(size_t)N * CC + roi] = rois[roi * 6 + 1];   // gt output
  }
}

// ---------- Kernel B: pure gather, no prologue ----------
__global__ __launch_bounds__(256) void roi_gather_kernel(
    const float* __restrict__ fm, const float* __restrict__ ws,
    float* __restrict__ out, int N) {
  const int bid = blockIdx.x;
  const int chunk = bid & 7;          // ~XCD id: XCD streams a 32-ch slice
  const int roi = bid >> 3;
  const int t = threadIdx.x;
  const int wave = t >> 6;
  const int lane = t & 63;

  __shared__ float4 stage[4][CPW][64];   // 32 KB, wave-private slices

  const float* W = ws + (size_t)roi * MSTRIDE;
  const int* I = (const int*)W;
  const int b = I[0], l2 = I[1], ngroups = I[2], x4lo = I[3];
  const int nx4 = 1 << l2;
  const int rowstep = 64 >> l2;
  const int ri = lane >> l2;
  const int xi = lane & (nx4 - 1);
  const int col4 = min(x4lo + xi, 31);           // clamp: pad lanes stay in-plane
  const float4 wx4 = *(const float4*)(W + 136 + (xi << 2));  // 0 for xi>=x4cnt

  const int c0 = chunk * 32 + wave * CPW;
  const float* cb = fm + ((size_t)b * CC + c0) * PLANE + (col4 << 2);

  // prefetch all row weights/offsets into registers (static indices, rule #20)
  float rw[7]; int ro[7];
  #pragma unroll
  for (int g = 0; g < 7; ++g) {
    const bool v = g < ngroups;
    const int si = v ? (g * rowstep + ri) : 0;   // si < 64 (zero-padded slots)
    rw[g] = v ? W[4 + si] : 0.f;
    ro[g] = v ? I[68 + si] : 0;
  }

  float acc[CPW];
  #pragma unroll
  for (int c = 0; c < CPW; ++c) acc[c] = 0.f;

  float* sb = (float*)&stage[wave][0][0];

  #pragma unroll
  for (int g = 0; g < 7; ++g) {
    if (g < ngroups) {                 // wave-uniform
      const float* p = cb + ro[g];
      #pragma unroll
      for (int c = 0; c < CPW; ++c) gload_lds16(p + c * PLANE, sb + (c << 8));
      asm volatile("s_waitcnt vmcnt(0)" ::: "memory");
      __builtin_amdgcn_sched_barrier(0);
      const float w0 = wx4.x * rw[g], w1 = wx4.y * rw[g];
      const float w2 = wx4.z * rw[g], w3 = wx4.w * rw[g];
      #pragma unroll
      for (int c = 0; c < CPW; ++c) {
        const float4 v = stage[wave][c][lane];
        acc[c] = fmaf(w0, v.x, acc[c]);
        acc[c] = fmaf(w1, v.y, acc[c]);
        acc[c] = fmaf(w2, v.z, acc[c]);
        acc[c] = fmaf(w3, v.w, acc[c]);
      }
      __builtin_amdgcn_sched_barrier(0);   // pin: consume(g) before issue(g+1)
    }
  }

  // ---- 64-lane reduce per channel, lane c writes channel c ----
  const size_t obase = (size_t)roi * CC + c0;
  #pragma unroll
  for (int c = 0; c < CPW; ++c) {
    float v = acc[c];
    #pragma unroll
    for (int m = 32; m >= 1; m >>= 1) v += __shfl_xor(v, m, 64);
    if (lane == c) out[obase + c] = v * (1.0f / 196.0f);
  }
}

extern "C" void kernel_launch(void* const* d_in, const int* in_sizes, int n_in,
                              void* d_out, int out_size, void* d_ws, size_t ws_size,
                              hipStream_t stream) {
  const float* fm   = (const float*)d_in[0];
  const float* rois = (const float*)d_in[1];
  float* out = (float*)d_out;
  float* ws  = (float*)d_ws;
  const int N = in_sizes[1] / 6;
  roi_meta_kernel<<<N, 64, 0, stream>>>(rois, ws, out, N);
  roi_gather_kernel<<<N * NCHUNK, 256, 0, stream>>>(fm, ws, out, N);
}